// Round 1
// baseline (247.760 us; speedup 1.0000x reference)
//
#include <hip/hip_runtime.h>
#include <math.h>

// DLP loss: ce(scores,target) + 25 * sum_i sum_{k<m_i} ||f_i - f_{nbr_k}/m_i||^2
// where nbr = m_i = min(#same-label (excl self), 20) nearest neighbors by
// eps-shifted L1 distance.
//
// Structure:
//  K1 ce_kernel     : 1 block. writes d_out[0] = cross-entropy (also inits out).
//  K2 dist_kernel   : 64x64 tiles, 4x4 reg blocking. D[i,j] (masked, +inf) -> d_ws (16MB).
//  K3 select_kernel : 1 wave / row. top-20 extraction from LDS row + contribution atomicAdd.

constexpr float EPS      = 1e-6f;
constexpr int   KSEL     = 20;
constexpr float LAM_HALF = 25.0f;   // 50 * 0.5

#define TILE 64
#define CK   64
#define LDP  (CK + 1)   // +1 pad: LDS scalar reads broadcast / 2-way only

__device__ __forceinline__ float finf() { return __builtin_inff(); }

// ---------------- K1: init out + cross entropy (mean) ----------------
__global__ __launch_bounds__(256) void ce_kernel(const float* __restrict__ scores,
                                                 const int* __restrict__ target,
                                                 float* __restrict__ out,
                                                 int N, int NC) {
    int tid = threadIdx.x;
    float acc = 0.f;
    for (int r = tid; r < N; r += 256) {
        const float* s = scores + (size_t)r * NC;
        float mx = -3.4e38f;
        for (int c = 0; c < NC; ++c) mx = fmaxf(mx, s[c]);
        float sum = 0.f;
        for (int c = 0; c < NC; ++c) sum += __expf(s[c] - mx);
        float lse = mx + __logf(sum);
        acc += lse - s[target[r]];
    }
    __shared__ float red[4];
    for (int o = 32; o > 0; o >>= 1) acc += __shfl_down(acc, o, 64);
    int wid = tid >> 6, lane = tid & 63;
    if (lane == 0) red[wid] = acc;
    __syncthreads();
    if (tid == 0) out[0] = (red[0] + red[1] + red[2] + red[3]) / (float)N;
}

// ---------------- K2: masked pairwise eps-shifted L1 distances ----------------
// D[i][j] = sum_c |F[i][c] - F[j][c] + EPS|  if same label && i!=j, else +inf
__global__ __launch_bounds__(256) void dist_kernel(const float* __restrict__ F,
                                                   const int* __restrict__ T,
                                                   float* __restrict__ D,
                                                   int N, int C) {
    __shared__ float As[TILE][LDP];   // i-rows  [row][c]
    __shared__ float Bs[TILE][LDP];   // j-rows  [row][c]
    const int tid = threadIdx.x;
    const int tx = tid & 15;          // -> j (coalesced stores)
    const int ty = tid >> 4;          // -> i
    const int i0 = blockIdx.y * TILE;
    const int j0 = blockIdx.x * TILE;

    float acc[4][4];
#pragma unroll
    for (int r = 0; r < 4; ++r)
#pragma unroll
        for (int s = 0; s < 4; ++s) acc[r][s] = 0.f;

    for (int ck = 0; ck < C; ck += CK) {
        // stage 64 rows x 64 c for both tiles; float4 global loads, scalar LDS writes
#pragma unroll
        for (int it = 0; it < (TILE * CK / 4) / 256; ++it) {
            int l   = tid + it * 256;
            int row = l >> 4;            // 0..63
            int c4  = (l & 15) << 2;     // 0,4,...,60
            float4 av = *(const float4*)&F[(size_t)(i0 + row) * C + ck + c4];
            As[row][c4 + 0] = av.x; As[row][c4 + 1] = av.y;
            As[row][c4 + 2] = av.z; As[row][c4 + 3] = av.w;
            float4 bv = *(const float4*)&F[(size_t)(j0 + row) * C + ck + c4];
            Bs[row][c4 + 0] = bv.x; Bs[row][c4 + 1] = bv.y;
            Bs[row][c4 + 2] = bv.z; Bs[row][c4 + 3] = bv.w;
        }
        __syncthreads();
#pragma unroll 8
        for (int c = 0; c < CK; ++c) {
            float a[4], b[4];
#pragma unroll
            for (int r = 0; r < 4; ++r) a[r] = As[ty * 4 + r][c] + EPS;
#pragma unroll
            for (int s = 0; s < 4; ++s) b[s] = Bs[tx * 4 + s][c];
#pragma unroll
            for (int r = 0; r < 4; ++r)
#pragma unroll
                for (int s = 0; s < 4; ++s)
                    acc[r][s] += fabsf(a[r] - b[s]);
        }
        __syncthreads();
    }

    // epilogue: mask (same label, not self) and store float4-coalesced
    const int ibase = i0 + ty * 4;
    const int jbase = j0 + tx * 4;
    int tj[4];
#pragma unroll
    for (int s = 0; s < 4; ++s) tj[s] = T[jbase + s];
#pragma unroll
    for (int r = 0; r < 4; ++r) {
        int i = ibase + r;
        int ti = T[i];
        float4 o;
        o.x = (tj[0] == ti && (jbase + 0) != i) ? acc[r][0] : finf();
        o.y = (tj[1] == ti && (jbase + 1) != i) ? acc[r][1] : finf();
        o.z = (tj[2] == ti && (jbase + 2) != i) ? acc[r][2] : finf();
        o.w = (tj[3] == ti && (jbase + 3) != i) ? acc[r][3] : finf();
        *(float4*)&D[(size_t)i * N + jbase] = o;
    }
}

// ---------------- K3: per-row top-20 + neighbor-pull contribution ----------------
// one wave (64 threads) per row i
__global__ __launch_bounds__(64) void select_kernel(const float* __restrict__ F,
                                                    const float* __restrict__ D,
                                                    float* __restrict__ out,
                                                    int N, int C) {
    extern __shared__ float sd[];          // N floats: the distance row
    __shared__ int ssel[KSEL];
    const int i    = blockIdx.x;
    const int lane = threadIdx.x;
    const float* drow = D + (size_t)i * N;

    int cnt = 0;
    for (int j = lane; j < N; j += 64) {
        float v = drow[j];
        sd[j] = v;
        cnt += (v < 1e37f) ? 1 : 0;        // finite == valid same-label pair
    }
    for (int o = 32; o > 0; o >>= 1) cnt += __shfl_down(cnt, o, 64);
    cnt = __shfl(cnt, 0, 64);
    __syncthreads();

    const int m = min(cnt, KSEL);

    for (int k = 0; k < m; ++k) {
        float bv = finf();
        int   bj = N;
        for (int j = lane; j < N; j += 64) {
            float v = sd[j];
            if (v < bv) { bv = v; bj = j; }   // strict < keeps lowest index
        }
        for (int o = 32; o > 0; o >>= 1) {
            float ov = __shfl_down(bv, o, 64);
            int   oj = __shfl_down(bj, o, 64);
            if (ov < bv || (ov == bv && oj < bj)) { bv = ov; bj = oj; }
        }
        bj = __shfl(bj, 0, 64);
        if (lane == 0) { ssel[k] = bj; sd[bj] = finf(); }
        __syncthreads();
    }

    // contribution: sum_c (f_i[c] - f_j[c]/m)^2 over the m selected neighbors
    float inv = 1.f / (float)max(m, 1);
    float acc = 0.f;
    for (int k = 0; k < m; ++k) {
        int j = ssel[k];
        for (int c = lane; c < C; c += 64) {
            float d = F[(size_t)i * C + c] - F[(size_t)j * C + c] * inv;
            acc += d * d;
        }
    }
    for (int o = 32; o > 0; o >>= 1) acc += __shfl_down(acc, o, 64);
    if (lane == 0) atomicAdd(out, LAM_HALF * acc);
}

extern "C" void kernel_launch(void* const* d_in, const int* in_sizes, int n_in,
                              void* d_out, int out_size, void* d_ws, size_t ws_size,
                              hipStream_t stream) {
    const float* feature = (const float*)d_in[0];
    const float* scores  = (const float*)d_in[1];
    const int*   target  = (const int*)d_in[2];
    const int N  = in_sizes[2];
    const int C  = in_sizes[0] / N;
    const int NC = in_sizes[1] / N;
    float* out = (float*)d_out;
    float* D   = (float*)d_ws;                   // N*N*4 bytes (16 MB @ N=2048)

    ce_kernel<<<1, 256, 0, stream>>>(scores, target, out, N, NC);

    dim3 gb(N / TILE, N / TILE);
    dist_kernel<<<gb, 256, 0, stream>>>(feature, target, D, N, C);

    select_kernel<<<N, 64, (size_t)N * sizeof(float), stream>>>(feature, D, out, N, C);
}

// Round 2
// 200.546 us; speedup vs baseline: 1.2354x; 1.2354x over previous
//
#include <hip/hip_runtime.h>
#include <math.h>

// DLP loss: ce(scores,target) + 25 * sum_i sum_{k<m_i} ||f_i - f_{nbr_k}/m_i||^2
// m_i = min(#same-label (excl self), 20), neighbors by eps-shifted L1 distance.
//
//  K1 ce_kernel     : 1 block. d_out[0] = cross-entropy (also inits out).
//  K2 dist_kernel   : 64x64 tiles, 4x4 reg blocking, b128 LDS reads, eps folded
//                     into A-staging, strided-j mapping for conflict-free banks.
//  K3 select_kernel : 1 wave/row, distance row register-resident, 20 butterfly
//                     argmin extractions, fused neighbor-pull contribution.

constexpr float EPS      = 1e-6f;
constexpr int   KSEL     = 20;
constexpr float LAM_HALF = 25.0f;   // 50 * 0.5

#define TILE 64
#define CK   64
#define LDP  68   // pad 64->68: keeps 16B alignment for b128, spreads banks

__device__ __forceinline__ float finf() { return __builtin_inff(); }

// ---------------- K1: init out + cross entropy (mean) ----------------
__global__ __launch_bounds__(256) void ce_kernel(const float* __restrict__ scores,
                                                 const int* __restrict__ target,
                                                 float* __restrict__ out,
                                                 int N, int NC) {
    int tid = threadIdx.x;
    float acc = 0.f;
    for (int r = tid; r < N; r += 256) {
        const float* s = scores + (size_t)r * NC;
        float mx = -3.4e38f;
        for (int c = 0; c < NC; ++c) mx = fmaxf(mx, s[c]);
        float sum = 0.f;
        for (int c = 0; c < NC; ++c) sum += __expf(s[c] - mx);
        float lse = mx + __logf(sum);
        acc += lse - s[target[r]];
    }
    __shared__ float red[4];
    for (int o = 32; o > 0; o >>= 1) acc += __shfl_down(acc, o, 64);
    int wid = tid >> 6, lane = tid & 63;
    if (lane == 0) red[wid] = acc;
    __syncthreads();
    if (tid == 0) out[0] = (red[0] + red[1] + red[2] + red[3]) / (float)N;
}

// ---------------- K2: masked pairwise eps-shifted L1 distances ----------------
// D[i][j] = sum_c |(F[i][c]+EPS) - F[j][c]|  if same label && i!=j, else +inf
// thread (tx,ty): i-rows = i0 + ty*4 + r (r<4), j-cols = j0 + tx + 16*s (s<4)
__global__ __launch_bounds__(256) void dist_kernel(const float* __restrict__ F,
                                                   const int* __restrict__ T,
                                                   float* __restrict__ D,
                                                   int N, int C) {
    __shared__ float As[TILE][LDP];   // f_i + EPS
    __shared__ float Bs[TILE][LDP];   // f_j
    const int tid = threadIdx.x;
    const int tx = tid & 15;
    const int ty = tid >> 4;
    const int i0 = blockIdx.y * TILE;
    const int j0 = blockIdx.x * TILE;

    float acc[4][4];
#pragma unroll
    for (int r = 0; r < 4; ++r)
#pragma unroll
        for (int s = 0; s < 4; ++s) acc[r][s] = 0.f;

    for (int ck = 0; ck < C; ck += CK) {
        // stage: 4 float4 global loads per array per thread-group pass,
        // b128 LDS writes (row-major matches global layout, no transpose)
#pragma unroll
        for (int it = 0; it < (TILE * CK / 4) / 256; ++it) {
            int l   = tid + it * 256;
            int row = l >> 4;            // 0..63
            int c4  = (l & 15) << 2;     // 0,4,...,60
            float4 av = *(const float4*)&F[(size_t)(i0 + row) * C + ck + c4];
            av.x += EPS; av.y += EPS; av.z += EPS; av.w += EPS;
            *(float4*)&As[row][c4] = av;
            float4 bv = *(const float4*)&F[(size_t)(j0 + row) * C + ck + c4];
            *(float4*)&Bs[row][c4] = bv;
        }
        __syncthreads();
#pragma unroll 4
        for (int c4 = 0; c4 < CK; c4 += 4) {
            float4 a[4], b[4];
#pragma unroll
            for (int r = 0; r < 4; ++r) a[r] = *(const float4*)&As[ty * 4 + r][c4];
#pragma unroll
            for (int s = 0; s < 4; ++s) b[s] = *(const float4*)&Bs[tx + 16 * s][c4];
#pragma unroll
            for (int r = 0; r < 4; ++r)
#pragma unroll
                for (int s = 0; s < 4; ++s) {
                    acc[r][s] += (fabsf(a[r].x - b[s].x) + fabsf(a[r].y - b[s].y))
                               + (fabsf(a[r].z - b[s].z) + fabsf(a[r].w - b[s].w));
                }
        }
        __syncthreads();
    }

    // epilogue: mask (same label, not self), scalar stores (lane-consecutive j)
    int ti[4], tj[4];
#pragma unroll
    for (int r = 0; r < 4; ++r) ti[r] = T[i0 + ty * 4 + r];
#pragma unroll
    for (int s = 0; s < 4; ++s) tj[s] = T[j0 + tx + 16 * s];
#pragma unroll
    for (int r = 0; r < 4; ++r) {
        const int i = i0 + ty * 4 + r;
#pragma unroll
        for (int s = 0; s < 4; ++s) {
            const int j = j0 + tx + 16 * s;
            D[(size_t)i * N + j] = (tj[s] == ti[r] && j != i) ? acc[r][s] : finf();
        }
    }
}

// ---------------- K3: per-row top-20 + neighbor-pull contribution ----------------
// one wave per row; distance row lives in 32 registers per lane.
// slot (q,e) of lane l holds j = 4*(q*64 + l) + e
__global__ __launch_bounds__(64) void select_kernel(const float* __restrict__ F,
                                                    const float* __restrict__ D,
                                                    float* __restrict__ out,
                                                    int N, int C) {
    __shared__ int ssel[KSEL];
    const int i    = blockIdx.x;
    const int lane = threadIdx.x;
    const float4* drow = (const float4*)(D + (size_t)i * N);

    float v[32];
#pragma unroll
    for (int q = 0; q < 8; ++q) {
        float4 t = drow[q * 64 + lane];
        v[q * 4 + 0] = t.x; v[q * 4 + 1] = t.y;
        v[q * 4 + 2] = t.z; v[q * 4 + 3] = t.w;
    }

    float lmin = finf();
#pragma unroll
    for (int s = 0; s < 32; ++s) lmin = fminf(lmin, v[s]);

    int m = 0;
    for (int k = 0; k < KSEL; ++k) {
        float w = lmin;
#pragma unroll
        for (int o = 1; o < 64; o <<= 1) w = fminf(w, __shfl_xor(w, o, 64));
        if (!(w < 1e37f)) break;         // fewer than KSEL valid neighbors
        unsigned long long mask = __ballot(lmin == w);
        int winner = (int)__builtin_ctzll(mask);
        if (lane == winner) {
            bool found = false;
            int  jw = 0;
#pragma unroll
            for (int s = 0; s < 32; ++s) {
                bool hit = !found && (v[s] == w);
                if (hit) { jw = 4 * ((s >> 2) * 64 + lane) + (s & 3); v[s] = finf(); found = true; }
            }
            ssel[k] = jw;
            float nm = finf();
#pragma unroll
            for (int s = 0; s < 32; ++s) nm = fminf(nm, v[s]);
            lmin = nm;
        }
        ++m;
    }
    __syncthreads();                      // ssel visibility for all lanes

    if (m == 0) return;

    // contribution: sum_c (f_i[c] - f_j[c]/m)^2 over the m selected neighbors
    const float inv = 1.f / (float)m;
    float4 fi = ((const float4*)(F + (size_t)i * C))[lane];   // c = 4*lane..+3
    float acc = 0.f;
    for (int k = 0; k < m; ++k) {
        const int j = ssel[k];
        float4 fj = ((const float4*)(F + (size_t)j * C))[lane];
        float dx = fi.x - fj.x * inv;
        float dy = fi.y - fj.y * inv;
        float dz = fi.z - fj.z * inv;
        float dw = fi.w - fj.w * inv;
        acc += (dx * dx + dy * dy) + (dz * dz + dw * dw);
    }
    for (int o = 32; o > 0; o >>= 1) acc += __shfl_down(acc, o, 64);
    if (lane == 0) atomicAdd(out, LAM_HALF * acc);
}

extern "C" void kernel_launch(void* const* d_in, const int* in_sizes, int n_in,
                              void* d_out, int out_size, void* d_ws, size_t ws_size,
                              hipStream_t stream) {
    const float* feature = (const float*)d_in[0];
    const float* scores  = (const float*)d_in[1];
    const int*   target  = (const int*)d_in[2];
    const int N  = in_sizes[2];
    const int C  = in_sizes[0] / N;
    const int NC = in_sizes[1] / N;
    float* out = (float*)d_out;
    float* D   = (float*)d_ws;                   // N*N*4 bytes (16 MB @ N=2048)

    ce_kernel<<<1, 256, 0, stream>>>(scores, target, out, N, NC);

    dim3 gb(N / TILE, N / TILE);
    dist_kernel<<<gb, 256, 0, stream>>>(feature, target, D, N, C);

    select_kernel<<<N, 64, 0, stream>>>(feature, D, out, N, C);
}

// Round 3
// 173.567 us; speedup vs baseline: 1.4275x; 1.1554x over previous
//
#include <hip/hip_runtime.h>
#include <math.h>

// DLP loss: ce(scores,target) + 25 * sum_i sum_{k<m_i} ||f_i - f_{nbr_k}/m_i||^2
// m_i = min(#same-label (excl self), 20), neighbors by eps-shifted L1 distance.
//
//  K1 ce_kernel     : 1 block. d_out[0] = cross-entropy.
//  K2 dist_kernel   : upper-triangle 64x64 tiles (528 blocks), 4x4 reg blocking,
//                     b128 LDS reads, eps folded into A-staging, mirror-store
//                     off-diagonal tiles (eps asymmetry ~5e-4 << threshold).
//  K3 select_kernel : 1 wave/row, row register-resident, <=20 butterfly argmin
//                     extractions, contribution written to D[i,i] (no atomics).
//  K4 reduce_kernel : 1 block. out[0] += sum_i D[i,i].

constexpr float EPS      = 1e-6f;
constexpr int   KSEL     = 20;
constexpr float LAM_HALF = 25.0f;   // 50 * 0.5

#define TILE 64
#define CK   64
#define LDP  68   // pad 64->68: 16B-aligned rows, conflict-free strided-j reads

__device__ __forceinline__ float finf() { return __builtin_inff(); }

// ---------------- K1: cross entropy (mean) ----------------
__global__ __launch_bounds__(256) void ce_kernel(const float* __restrict__ scores,
                                                 const int* __restrict__ target,
                                                 float* __restrict__ out,
                                                 int N, int NC) {
    int tid = threadIdx.x;
    float acc = 0.f;
    for (int r = tid; r < N; r += 256) {
        const float* s = scores + (size_t)r * NC;
        float mx = -3.4e38f;
        for (int c = 0; c < NC; ++c) mx = fmaxf(mx, s[c]);
        float sum = 0.f;
        for (int c = 0; c < NC; ++c) sum += __expf(s[c] - mx);
        float lse = mx + __logf(sum);
        acc += lse - s[target[r]];
    }
    __shared__ float red[4];
    for (int o = 32; o > 0; o >>= 1) acc += __shfl_down(acc, o, 64);
    int wid = tid >> 6, lane = tid & 63;
    if (lane == 0) red[wid] = acc;
    __syncthreads();
    if (tid == 0) out[0] = (red[0] + red[1] + red[2] + red[3]) / (float)N;
}

// ---------------- K2: masked pairwise eps-shifted L1, upper triangle ----------------
// D[i][j] = sum_c |(F[i][c]+EPS) - F[j][c]| if same label && i!=j else +inf;
// off-diagonal tiles mirrored to D[j][i].
__global__ __launch_bounds__(256) void dist_kernel(const float* __restrict__ F,
                                                   const int* __restrict__ T,
                                                   float* __restrict__ D,
                                                   int N, int C, int NB) {
    // triangular decode: blockIdx.x -> (bi, bj), bi <= bj < NB
    const int idx = blockIdx.x;
    int bi = (int)((2.f * NB + 1.f - sqrtf((2.f * NB + 1.f) * (2.f * NB + 1.f) - 8.f * idx)) * 0.5f);
    while ((bi + 1) * NB - ((bi + 1) * bi) / 2 <= idx) ++bi;
    while (bi * NB - (bi * (bi - 1)) / 2 > idx) --bi;
    const int bj = bi + (idx - (bi * NB - (bi * (bi - 1)) / 2));
    const int i0 = bi * TILE;
    const int j0 = bj * TILE;
    const bool mirror = (bi != bj);

    __shared__ float As[TILE][LDP];   // f_i + EPS
    __shared__ float Bs[TILE][LDP];   // f_j
    const int tid = threadIdx.x;
    const int tx = tid & 15;
    const int ty = tid >> 4;

    float acc[4][4];
#pragma unroll
    for (int r = 0; r < 4; ++r)
#pragma unroll
        for (int s = 0; s < 4; ++s) acc[r][s] = 0.f;

    for (int ck = 0; ck < C; ck += CK) {
#pragma unroll
        for (int it = 0; it < (TILE * CK / 4) / 256; ++it) {
            int l   = tid + it * 256;
            int row = l >> 4;
            int c4  = (l & 15) << 2;
            float4 av = *(const float4*)&F[(size_t)(i0 + row) * C + ck + c4];
            av.x += EPS; av.y += EPS; av.z += EPS; av.w += EPS;
            *(float4*)&As[row][c4] = av;
            float4 bv = *(const float4*)&F[(size_t)(j0 + row) * C + ck + c4];
            *(float4*)&Bs[row][c4] = bv;
        }
        __syncthreads();
#pragma unroll 4
        for (int c4 = 0; c4 < CK; c4 += 4) {
            float4 a[4], b[4];
#pragma unroll
            for (int r = 0; r < 4; ++r) a[r] = *(const float4*)&As[ty * 4 + r][c4];
#pragma unroll
            for (int s = 0; s < 4; ++s) b[s] = *(const float4*)&Bs[tx + 16 * s][c4];
#pragma unroll
            for (int r = 0; r < 4; ++r)
#pragma unroll
                for (int s = 0; s < 4; ++s) {
                    acc[r][s] += (fabsf(a[r].x - b[s].x) + fabsf(a[r].y - b[s].y))
                               + (fabsf(a[r].z - b[s].z) + fabsf(a[r].w - b[s].w));
                }
        }
        __syncthreads();
    }

    int ti[4], tj[4];
#pragma unroll
    for (int r = 0; r < 4; ++r) ti[r] = T[i0 + ty * 4 + r];
#pragma unroll
    for (int s = 0; s < 4; ++s) tj[s] = T[j0 + tx + 16 * s];
#pragma unroll
    for (int r = 0; r < 4; ++r) {
        const int i = i0 + ty * 4 + r;
#pragma unroll
        for (int s = 0; s < 4; ++s) {
            const int j = j0 + tx + 16 * s;
            float val = (tj[s] == ti[r] && j != i) ? acc[r][s] : finf();
            D[(size_t)i * N + j] = val;
            if (mirror) D[(size_t)j * N + i] = val;   // eps asymmetry << tolerance
        }
    }
}

// ---------------- K3: per-row top-20 + contribution -> D[i,i] ----------------
// one wave per row; slot (q,e) of lane l holds j = 4*(q*64 + l) + e
__global__ __launch_bounds__(64) void select_kernel(const float* __restrict__ F,
                                                    float* __restrict__ D,
                                                    int N, int C) {
    __shared__ int ssel[KSEL];
    const int i    = blockIdx.x;
    const int lane = threadIdx.x;
    const float4* drow = (const float4*)(D + (size_t)i * N);

    float v[32];
#pragma unroll
    for (int q = 0; q < 8; ++q) {
        float4 t = drow[q * 64 + lane];
        v[q * 4 + 0] = t.x; v[q * 4 + 1] = t.y;
        v[q * 4 + 2] = t.z; v[q * 4 + 3] = t.w;
    }

    float lmin = finf();
#pragma unroll
    for (int s = 0; s < 32; ++s) lmin = fminf(lmin, v[s]);

    int m = 0;
    for (int k = 0; k < KSEL; ++k) {
        float w = lmin;
#pragma unroll
        for (int o = 1; o < 64; o <<= 1) w = fminf(w, __shfl_xor(w, o, 64));
        if (!(w < 1e37f)) break;
        unsigned long long mask = __ballot(lmin == w);
        int winner = (int)__builtin_ctzll(mask);
        if (lane == winner) {
            bool found = false;
            int  jw = 0;
#pragma unroll
            for (int s = 0; s < 32; ++s) {
                bool hit = !found && (v[s] == w);
                if (hit) { jw = 4 * ((s >> 2) * 64 + lane) + (s & 3); v[s] = finf(); found = true; }
            }
            ssel[k] = jw;
            float nm = finf();
#pragma unroll
            for (int s = 0; s < 32; ++s) nm = fminf(nm, v[s]);
            lmin = nm;
        }
        ++m;
    }
    __syncthreads();

    float total = 0.f;
    if (m > 0) {
        const float inv = 1.f / (float)m;
        float4 fi = ((const float4*)(F + (size_t)i * C))[lane];
        float acc = 0.f;
        for (int k = 0; k < m; ++k) {
            const int j = ssel[k];
            float4 fj = ((const float4*)(F + (size_t)j * C))[lane];
            float dx = fi.x - fj.x * inv;
            float dy = fi.y - fj.y * inv;
            float dz = fi.z - fj.z * inv;
            float dw = fi.w - fj.w * inv;
            acc += (dx * dx + dy * dy) + (dz * dz + dw * dw);
        }
        for (int o = 32; o > 0; o >>= 1) acc += __shfl_down(acc, o, 64);
        total = LAM_HALF * acc;
    }
    if (lane == 0) D[(size_t)i * N + i] = total;   // per-row partial, no atomics
}

// ---------------- K4: out[0] += sum_i D[i,i] ----------------
__global__ __launch_bounds__(256) void reduce_kernel(const float* __restrict__ D,
                                                     float* __restrict__ out, int N) {
    int tid = threadIdx.x;
    float s = 0.f;
    for (int i = tid; i < N; i += 256) s += D[(size_t)i * N + i];
    __shared__ float red[4];
    for (int o = 32; o > 0; o >>= 1) s += __shfl_down(s, o, 64);
    int wid = tid >> 6, lane = tid & 63;
    if (lane == 0) red[wid] = s;
    __syncthreads();
    if (tid == 0) out[0] += red[0] + red[1] + red[2] + red[3];
}

extern "C" void kernel_launch(void* const* d_in, const int* in_sizes, int n_in,
                              void* d_out, int out_size, void* d_ws, size_t ws_size,
                              hipStream_t stream) {
    const float* feature = (const float*)d_in[0];
    const float* scores  = (const float*)d_in[1];
    const int*   target  = (const int*)d_in[2];
    const int N  = in_sizes[2];
    const int C  = in_sizes[0] / N;
    const int NC = in_sizes[1] / N;
    float* out = (float*)d_out;
    float* D   = (float*)d_ws;                   // N*N*4 bytes (16 MB @ N=2048)
    const int NB = N / TILE;

    ce_kernel<<<1, 256, 0, stream>>>(scores, target, out, N, NC);

    const int nblk = NB * (NB + 1) / 2;          // 528 upper-triangle tiles
    dist_kernel<<<nblk, 256, 0, stream>>>(feature, target, D, N, C, NB);

    select_kernel<<<N, 64, 0, stream>>>(feature, D, N, C);

    reduce_kernel<<<1, 256, 0, stream>>>(D, out, N);
}

// Round 4
// 162.199 us; speedup vs baseline: 1.5275x; 1.0701x over previous
//
#include <hip/hip_runtime.h>
#include <math.h>

// DLP loss: ce(scores,target) + 25 * sum_i sum_{k<m_i} ||f_i - f_{nbr_k}/m_i||^2
// m_i = min(#same-label (excl self), 20), neighbors by eps-shifted L1 distance.
//
//  K1 dist_kernel     : upper-triangle supertiles split into 64x32 blocks
//                       (1056 blocks -> ~6 blocks/CU by LDS), 4x2 reg blocking,
//                       b128 LDS reads, eps folded into A-staging, mirror-store
//                       for off-diagonal supertiles (eps asymmetry << tolerance).
//  K2 select_kernel   : 1 wave/row, row register-resident, <=20 butterfly argmin
//                       extractions, contribution written to D[i,i] (no atomics).
//  K3 finalize_kernel : 1 block. out[0] = cross-entropy + sum_i D[i,i].

constexpr float EPS      = 1e-6f;
constexpr int   KSEL     = 20;
constexpr float LAM_HALF = 25.0f;   // 50 * 0.5

#define TI   64
#define TJ   32
#define CK   64
#define LDP  68   // pad 64->68: 16B-aligned rows, 2-way-max bank aliasing (free)

__device__ __forceinline__ float finf() { return __builtin_inff(); }

// ---------------- K1: masked pairwise eps-shifted L1, upper triangle ----------------
// D[i][j] = sum_c |(F[i][c]+EPS) - F[j][c]| if same label && i!=j else +inf
__global__ __launch_bounds__(256) void dist_kernel(const float* __restrict__ F,
                                                   const int* __restrict__ T,
                                                   float* __restrict__ D,
                                                   int N, int C, int NB) {
    // blockIdx.x -> supertile (bi,bj) with bi<=bj<NB, plus j-half
    const int st   = blockIdx.x >> 1;
    const int half = blockIdx.x & 1;
    int bi = 0;
    while ((bi + 1) * NB - ((bi + 1) * bi) / 2 <= st) ++bi;
    const int bj = bi + (st - (bi * NB - (bi * (bi - 1)) / 2));
    const int i0 = bi * 64;
    const int j0 = bj * 64 + half * TJ;
    const bool mirror = (bi != bj);   // diagonal supertiles: direct stores only

    __shared__ float As[TI][LDP];   // f_i + EPS
    __shared__ float Bs[TJ][LDP];   // f_j
    const int tid = threadIdx.x;
    const int tx = tid & 15;          // j-group
    const int ty = tid >> 4;          // i-group

    float acc[4][2];
#pragma unroll
    for (int r = 0; r < 4; ++r)
#pragma unroll
        for (int s = 0; s < 2; ++s) acc[r][s] = 0.f;

    for (int ck = 0; ck < C; ck += CK) {
        // stage A: 64 rows x 64 c  (4 passes of 256 float4 slots)
#pragma unroll
        for (int it = 0; it < 4; ++it) {
            int l   = tid + it * 256;
            int row = l >> 4;
            int c4  = (l & 15) << 2;
            float4 av = *(const float4*)&F[(size_t)(i0 + row) * C + ck + c4];
            av.x += EPS; av.y += EPS; av.z += EPS; av.w += EPS;
            *(float4*)&As[row][c4] = av;
        }
        // stage B: 32 rows x 64 c  (2 passes)
#pragma unroll
        for (int it = 0; it < 2; ++it) {
            int l   = tid + it * 256;
            int row = l >> 4;
            int c4  = (l & 15) << 2;
            *(float4*)&Bs[row][c4] = *(const float4*)&F[(size_t)(j0 + row) * C + ck + c4];
        }
        __syncthreads();
#pragma unroll 4
        for (int c4 = 0; c4 < CK; c4 += 4) {
            float4 a[4], b[2];
#pragma unroll
            for (int r = 0; r < 4; ++r) a[r] = *(const float4*)&As[ty * 4 + r][c4];
#pragma unroll
            for (int s = 0; s < 2; ++s) b[s] = *(const float4*)&Bs[tx + 16 * s][c4];
#pragma unroll
            for (int r = 0; r < 4; ++r)
#pragma unroll
                for (int s = 0; s < 2; ++s) {
                    acc[r][s] += (fabsf(a[r].x - b[s].x) + fabsf(a[r].y - b[s].y))
                               + (fabsf(a[r].z - b[s].z) + fabsf(a[r].w - b[s].w));
                }
        }
        __syncthreads();
    }

    int ti[4], tj[2];
#pragma unroll
    for (int r = 0; r < 4; ++r) ti[r] = T[i0 + ty * 4 + r];
#pragma unroll
    for (int s = 0; s < 2; ++s) tj[s] = T[j0 + tx + 16 * s];
#pragma unroll
    for (int r = 0; r < 4; ++r) {
        const int i = i0 + ty * 4 + r;
#pragma unroll
        for (int s = 0; s < 2; ++s) {
            const int j = j0 + tx + 16 * s;
            float val = (tj[s] == ti[r] && j != i) ? acc[r][s] : finf();
            D[(size_t)i * N + j] = val;
            if (mirror) D[(size_t)j * N + i] = val;   // eps asymmetry << tolerance
        }
    }
}

// ---------------- K2: per-row top-20 + contribution -> D[i,i] ----------------
// one wave per row; slot (q,e) of lane l holds j = 4*(q*64 + l) + e
__global__ __launch_bounds__(64) void select_kernel(const float* __restrict__ F,
                                                    float* __restrict__ D,
                                                    int N, int C) {
    __shared__ int ssel[KSEL];
    const int i    = blockIdx.x;
    const int lane = threadIdx.x;
    const float4* drow = (const float4*)(D + (size_t)i * N);

    float v[32];
#pragma unroll
    for (int q = 0; q < 8; ++q) {
        float4 t = drow[q * 64 + lane];
        v[q * 4 + 0] = t.x; v[q * 4 + 1] = t.y;
        v[q * 4 + 2] = t.z; v[q * 4 + 3] = t.w;
    }

    float lmin = finf();
#pragma unroll
    for (int s = 0; s < 32; ++s) lmin = fminf(lmin, v[s]);

    int m = 0;
    for (int k = 0; k < KSEL; ++k) {
        float w = lmin;
#pragma unroll
        for (int o = 1; o < 64; o <<= 1) w = fminf(w, __shfl_xor(w, o, 64));
        if (!(w < 1e37f)) break;
        unsigned long long mask = __ballot(lmin == w);
        int winner = (int)__builtin_ctzll(mask);
        if (lane == winner) {
            bool found = false;
            int  jw = 0;
#pragma unroll
            for (int s = 0; s < 32; ++s) {
                bool hit = !found && (v[s] == w);
                if (hit) { jw = 4 * ((s >> 2) * 64 + lane) + (s & 3); v[s] = finf(); found = true; }
            }
            ssel[k] = jw;
            float nm = finf();
#pragma unroll
            for (int s = 0; s < 32; ++s) nm = fminf(nm, v[s]);
            lmin = nm;
        }
        ++m;
    }
    __syncthreads();

    float total = 0.f;
    if (m > 0) {
        const float inv = 1.f / (float)m;
        float4 fi = ((const float4*)(F + (size_t)i * C))[lane];
        float acc = 0.f;
        for (int k = 0; k < m; ++k) {
            const int j = ssel[k];
            float4 fj = ((const float4*)(F + (size_t)j * C))[lane];
            float dx = fi.x - fj.x * inv;
            float dy = fi.y - fj.y * inv;
            float dz = fi.z - fj.z * inv;
            float dw = fi.w - fj.w * inv;
            acc += (dx * dx + dy * dy) + (dz * dz + dw * dw);
        }
        for (int o = 32; o > 0; o >>= 1) acc += __shfl_down(acc, o, 64);
        total = LAM_HALF * acc;
    }
    if (lane == 0) D[(size_t)i * N + i] = total;   // per-row partial, no atomics
}

// ---------------- K3: out[0] = cross-entropy(mean) + sum_i D[i,i] ----------------
__global__ __launch_bounds__(256) void finalize_kernel(const float* __restrict__ scores,
                                                       const int* __restrict__ target,
                                                       const float* __restrict__ D,
                                                       float* __restrict__ out,
                                                       int N, int NC) {
    int tid = threadIdx.x;
    float ce = 0.f, dg = 0.f;
    for (int r = tid; r < N; r += 256) {
        const float* s = scores + (size_t)r * NC;
        float mx = -3.4e38f;
        for (int c = 0; c < NC; ++c) mx = fmaxf(mx, s[c]);
        float sum = 0.f;
        for (int c = 0; c < NC; ++c) sum += __expf(s[c] - mx);
        ce += mx + __logf(sum) - s[target[r]];
        dg += D[(size_t)r * N + r];
    }
    __shared__ float redc[4], redd[4];
    for (int o = 32; o > 0; o >>= 1) { ce += __shfl_down(ce, o, 64); dg += __shfl_down(dg, o, 64); }
    int wid = tid >> 6, lane = tid & 63;
    if (lane == 0) { redc[wid] = ce; redd[wid] = dg; }
    __syncthreads();
    if (tid == 0)
        out[0] = (redc[0] + redc[1] + redc[2] + redc[3]) / (float)N
               + (redd[0] + redd[1] + redd[2] + redd[3]);
}

extern "C" void kernel_launch(void* const* d_in, const int* in_sizes, int n_in,
                              void* d_out, int out_size, void* d_ws, size_t ws_size,
                              hipStream_t stream) {
    const float* feature = (const float*)d_in[0];
    const float* scores  = (const float*)d_in[1];
    const int*   target  = (const int*)d_in[2];
    const int N  = in_sizes[2];
    const int C  = in_sizes[0] / N;
    const int NC = in_sizes[1] / N;
    float* out = (float*)d_out;
    float* D   = (float*)d_ws;                   // N*N*4 bytes (16 MB @ N=2048)
    const int NB = N / 64;

    const int nblk = NB * (NB + 1) / 2 * 2;      // 528 supertiles x 2 j-halves
    dist_kernel<<<nblk, 256, 0, stream>>>(feature, target, D, N, C, NB);

    select_kernel<<<N, 64, 0, stream>>>(feature, D, N, C);

    finalize_kernel<<<1, 256, 0, stream>>>(scores, target, D, out, N, NC);
}